// Round 4
// baseline (586.730 us; speedup 1.0000x reference)
//
#include <hip/hip_runtime.h>
#include <hip/hip_bf16.h>

#define NVOX 200000
#define CCH  128
#define KTOT 384
#define EPS_BN 1e-5f
#define PB   625          // persistent blocks per axis
#define TPB  5            // tiles per block (625*5 = 3125 = 200000/64)
#define NTILE 3125        // tiles per axis

typedef __bf16 bf16x8 __attribute__((ext_vector_type(8)));
typedef __bf16 bf16x4 __attribute__((ext_vector_type(4)));
typedef float  floatx4 __attribute__((ext_vector_type(4)));

// ---- workspace layout (bytes) ----
#define XBF_OFF    0ull
#define XBF_BYTES  ((size_t)(NVOX + 1) * CCH * 2)      // bf16 features + zero row
#define WT_OFF     (XBF_OFF + XBF_BYTES)
#define WT_BYTES   ((size_t)3 * CCH * KTOT * 2)        // WT[a][c][k] bf16
#define OUTB_OFF   (WT_OFF + WT_BYTES)
#define OUTB_BYTES ((size_t)3 * NVOX * CCH * 2)        // pre-BN out, D-layout, bf16
#define STATS_OFF  (OUTB_OFF + OUTB_BYTES)
#define STATS_BYTES ((size_t)3 * 2 * CCH * 4)          // sum/sumsq fp32

// Fused prep: cast x -> bf16 (+ zero sentinel row), transpose W -> WT, zero stats.
__global__ void k_prep(const float* __restrict__ xf, __bf16* __restrict__ xbf,
                       const float* __restrict__ W, __bf16* __restrict__ wt,
                       float* __restrict__ stats) {
    int idx = blockIdx.x * blockDim.x + threadIdx.x;
    const int XC = (NVOX + 1) * 16;                    // 8-channel chunks
    if (idx < XC) {
        float v[8];
        if (idx < NVOX * 16) {
            const float4* p = (const float4*)xf + (size_t)idx * 2;
            float4 f0 = p[0], f1 = p[1];
            v[0] = f0.x; v[1] = f0.y; v[2] = f0.z; v[3] = f0.w;
            v[4] = f1.x; v[5] = f1.y; v[6] = f1.z; v[7] = f1.w;
        } else {
            #pragma unroll
            for (int j = 0; j < 8; ++j) v[j] = 0.0f;
        }
        bf16x8 o;
        #pragma unroll
        for (int j = 0; j < 8; ++j) o[j] = (__bf16)v[j];
        *((bf16x8*)xbf + idx) = o;
    } else if (idx < XC + 3 * CCH * KTOT) {
        int j = idx - XC;
        int k = j % KTOT; int rem = j / KTOT;
        int c = rem % CCH;  int a = rem / CCH;
        int s = k >> 7, k0 = k & 127;
        wt[j] = (__bf16)W[(((size_t)(a * 3 + s) * CCH) + k0) * CCH + c];
    } else if (idx < XC + 3 * CCH * KTOT + 768) {
        stats[idx - XC - 3 * CCH * KTOT] = 0.0f;
    }
}

// Persistent-block GEMM.
// - A staged via global_load_lds (gathered global src, linear LDS dest, XOR-swizzle
//   on BOTH source chunk choice and fragment read).
// - C stored directly in MFMA D-layout (bf16x4 per lane, coalesced) -- no smemO,
//   no LDS round-trip, no bank conflicts; k_final decodes the layout.
// - Sparsity skip: ~95% of prev/next rows are the zero row. Per (mt, src) group of
//   16 rows, if ALL rows are sentinel the A-reads + MFMAs are skipped (wave-uniform
//   scalar branch; skipped contributions are exact zeros -> bit-identical result).
// - 2 barriers/tile; stats in registers, one atomic set per block.
__launch_bounds__(256, 3)
__global__ void k_gemm(const __bf16* __restrict__ xbf, const __bf16* __restrict__ wt,
                       const int* __restrict__ nb, __bf16* __restrict__ outb,
                       float* __restrict__ stats) {
    __shared__ __align__(16) __bf16 smemA[64 * 384];   // A tile, linear (glds dest)
    __shared__ int s_pn[2][128];                       // double-buffered prev/next idx
    __shared__ int s_msk[2][2];                        // [buf][0]=prev 4-bit, [1]=next

    const int a    = blockIdx.y;
    const int tid  = threadIdx.x;
    const int w    = tid >> 6;
    const int lane = tid & 63;
    const int q    = lane >> 4;
    const int ln   = lane & 15;
    const int e    = ln & 7;       // row-XOR key for this lane's fragment rows

    // ---- B resident in registers for the whole block lifetime ----
    const __bf16* wbase = wt + (size_t)a * CCH * KTOT;
    bf16x8 B0[12], B1[12];
    #pragma unroll
    for (int ks = 0; ks < 12; ++ks) {
        B0[ks] = *(const bf16x8*)(wbase + (size_t)(w * 32 + ln) * KTOT + ks * 32 + q * 8);
        B1[ks] = *(const bf16x8*)(wbase + (size_t)(w * 32 + 16 + ln) * KTOT + ks * 32 + q * 8);
    }

    // per-column stats accumulated in registers across all tiles
    float s0 = 0.f, ss0 = 0.f, s1 = 0.f, ss1 = 0.f;

    // ---- prologue: pn + masks for tile 0; pn for tile 1 in r_pn ----
    int r_pn = 0;
    if (tid < 128) {
        const size_t nbase = (size_t)(a * 2 + (tid >> 6)) * NVOX + (tid & 63);
        r_pn = nb[nbase + blockIdx.x * 64];
        s_pn[0][tid] = r_pn;
    }
    {
        unsigned long long m = 0;
        if (tid < 128) m = __ballot(r_pn == NVOX);
        if (tid == 0 || tid == 64) {
            int pm = 0;
            #pragma unroll
            for (int gg = 0; gg < 4; ++gg)
                if (((m >> (gg * 16)) & 0xFFFFull) == 0xFFFFull) pm |= 1 << gg;
            s_msk[0][tid >> 6] = pm;
        }
    }
    if (tid < 128)
        r_pn = nb[(size_t)(a * 2 + (tid >> 6)) * NVOX + (tid & 63) + (blockIdx.x + PB) * 64];
    __syncthreads();

    for (int ti = 0; ti < TPB; ++ti) {
        const int tIdx = blockIdx.x + ti * PB;
        const int row0 = tIdx * 64;
        const int buf  = ti & 1;

        // ---- issue gathered A tile straight into LDS (3072 x 16B chunks) ----
        #pragma unroll
        for (int it = 0; it < 12; ++it) {
            int p    = it * 256 + tid;       // linear LDS chunk index
            int r    = p / 48;               // row 0..63
            int spos = p - r * 48;           // swizzled slot within row
            int slog = spos ^ (r & 7);       // logical chunk: src*16 + ch
            int src  = slog >> 4, ch = slog & 15;
            int g    = (src == 1) ? (row0 + r) : s_pn[buf][(src >> 1) * 64 + r];
            const __bf16* gp = xbf + (size_t)g * CCH + ch * 8;
            __builtin_amdgcn_global_load_lds(
                (const __attribute__((address_space(1))) void*)gp,
                (__attribute__((address_space(3))) void*)(&smemA[(it * 256 + w * 64) * 8]),
                16, 0, 0);
        }
        // publish next tile's pn + validity masks (register ballot, no LDS read)
        if (ti + 1 < TPB) {
            if (tid < 128) s_pn[buf ^ 1][tid] = r_pn;
            unsigned long long m = 0;
            if (tid < 128) m = __ballot(r_pn == NVOX);
            if (tid == 0 || tid == 64) {
                int pm = 0;
                #pragma unroll
                for (int gg = 0; gg < 4; ++gg)
                    if (((m >> (gg * 16)) & 0xFFFFull) == 0xFFFFull) pm |= 1 << gg;
                s_msk[buf ^ 1][tid >> 6] = pm;
            }
        }
        __syncthreads();   // BAR1: A landed (vmcnt drain) + prev stores drained

        // prefetch pn for tile ti+2 (latency hidden under MFMA)
        if (ti + 2 < TPB && tid < 128)
            r_pn = nb[(size_t)(a * 2 + (tid >> 6)) * NVOX
                      + (blockIdx.x + (ti + 2) * PB) * 64 + (tid & 63)];

        const int pm = __builtin_amdgcn_readfirstlane(s_msk[buf][0]);
        const int nm = __builtin_amdgcn_readfirstlane(s_msk[buf][1]);

        // ---- MFMA K-loop with per-(mt,src) sparsity skip ----
        floatx4 acc0[4], acc1[4];
        #pragma unroll
        for (int mt = 0; mt < 4; ++mt)
            #pragma unroll
            for (int r = 0; r < 4; ++r) { acc0[mt][r] = 0.0f; acc1[mt][r] = 0.0f; }

        #pragma unroll
        for (int mt = 0; mt < 4; ++mt) {
            const int rr = mt * 16 + ln;
            #pragma unroll
            for (int ks = 4; ks < 8; ++ks) {        // self: always
                bf16x8 afr = *(const bf16x8*)(&smemA[rr * 384 + (((ks * 4 + q) ^ e) * 8)]);
                acc0[mt] = __builtin_amdgcn_mfma_f32_16x16x32_bf16(afr, B0[ks], acc0[mt], 0, 0, 0);
                acc1[mt] = __builtin_amdgcn_mfma_f32_16x16x32_bf16(afr, B1[ks], acc1[mt], 0, 0, 0);
            }
            if (!((pm >> mt) & 1)) {
                #pragma unroll
                for (int ks = 0; ks < 4; ++ks) {    // prev
                    bf16x8 afr = *(const bf16x8*)(&smemA[rr * 384 + (((ks * 4 + q) ^ e) * 8)]);
                    acc0[mt] = __builtin_amdgcn_mfma_f32_16x16x32_bf16(afr, B0[ks], acc0[mt], 0, 0, 0);
                    acc1[mt] = __builtin_amdgcn_mfma_f32_16x16x32_bf16(afr, B1[ks], acc1[mt], 0, 0, 0);
                }
            }
            if (!((nm >> mt) & 1)) {
                #pragma unroll
                for (int ks = 8; ks < 12; ++ks) {   // next
                    bf16x8 afr = *(const bf16x8*)(&smemA[rr * 384 + (((ks * 4 + q) ^ e) * 8)]);
                    acc0[mt] = __builtin_amdgcn_mfma_f32_16x16x32_bf16(afr, B0[ks], acc0[mt], 0, 0, 0);
                    acc1[mt] = __builtin_amdgcn_mfma_f32_16x16x32_bf16(afr, B1[ks], acc1[mt], 0, 0, 0);
                }
            }
        }

        // ---- stats into register accumulators ----
        #pragma unroll
        for (int mt = 0; mt < 4; ++mt)
            #pragma unroll
            for (int r = 0; r < 4; ++r) {
                float v0 = acc0[mt][r]; s0 += v0; ss0 += v0 * v0;
                float v1 = acc1[mt][r]; s1 += v1; ss1 += v1 * v1;
            }

        __syncthreads();   // BAR2: all A-reads done; next glds may overwrite smemA

        // ---- direct D-layout stores: slot = ((w*2+nt)*4+mt)*256 + lane*4 + r ----
        {
            __bf16* ob = outb + ((size_t)(a * NTILE + tIdx)) * 8192 + lane * 4;
            #pragma unroll
            for (int mt = 0; mt < 4; ++mt) {
                bf16x4 v0, v1;
                #pragma unroll
                for (int r = 0; r < 4; ++r) { v0[r] = (__bf16)acc0[mt][r]; v1[r] = (__bf16)acc1[mt][r]; }
                *(bf16x4*)(ob + ((w * 2 + 0) * 4 + mt) * 256) = v0;
                *(bf16x4*)(ob + ((w * 2 + 1) * 4 + mt) * 256) = v1;
            }
        }
        // stores drain at next tile's BAR1 (covered by glds issue + other blocks)
    }

    // ---- epilogue: quad-reduce stats, one atomic set per block ----
    s0 += __shfl_xor(s0, 16); ss0 += __shfl_xor(ss0, 16);
    s0 += __shfl_xor(s0, 32); ss0 += __shfl_xor(ss0, 32);
    s1 += __shfl_xor(s1, 16); ss1 += __shfl_xor(ss1, 16);
    s1 += __shfl_xor(s1, 32); ss1 += __shfl_xor(ss1, 32);
    if (lane < 16) {
        int c0 = w * 32 + lane, c1 = w * 32 + 16 + lane;
        atomicAdd(&stats[a * 2 * CCH + c0], s0);
        atomicAdd(&stats[a * 2 * CCH + CCH + c0], ss0);
        atomicAdd(&stats[a * 2 * CCH + c1], s1);
        atomicAdd(&stats[a * 2 * CCH + CCH + c1], ss1);
    }
}

// Decode D-layout outb, apply BN+sigmoid, sum over axes, multiply by features.
// Chunk c -> (tile t, group g in [0,32), lane): 4 consecutive rows, one column.
__launch_bounds__(256)
__global__ void k_final(const __bf16* __restrict__ outb, const float* __restrict__ xf,
                        const float* __restrict__ stats, const float* __restrict__ gamma,
                        const float* __restrict__ beta, float* __restrict__ out) {
    __shared__ float lsc[384], lsh[384];
    int tid = threadIdx.x;
    for (int i = tid; i < 384; i += 256) {
        int a = i >> 7, c = i & 127;
        float mu  = stats[a * 256 + c] * (1.0f / NVOX);
        float var = stats[a * 256 + 128 + c] * (1.0f / NVOX) - mu * mu;
        float rs  = rsqrtf(var + EPS_BN);
        float g = gamma[i], b = beta[i];
        lsc[i] = rs * g;
        lsh[i] = b - mu * rs * g;
    }
    __syncthreads();
    const int total = NTILE * 2048;     // 8B chunks per axis
    for (int c = blockIdx.x * 256 + tid; c < total; c += gridDim.x * 256) {
        int t     = c >> 11;
        int cc    = c & 2047;
        int g     = cc >> 6;            // ((w*2+nt)*4 + mt)
        int lane2 = cc & 63;
        int mt    = g & 3, h = g >> 2;  // h = w*2+nt
        int qq    = lane2 >> 4, lnn = lane2 & 15;
        int col   = h * 16 + lnn;       // == w*32 + nt*16 + ln
        int row   = t * 64 + mt * 16 + qq * 4;
        float r[4] = {0.f, 0.f, 0.f, 0.f};
        #pragma unroll
        for (int a = 0; a < 3; ++a) {
            bf16x4 o = *(const bf16x4*)(outb + ((size_t)(a * NTILE + t)) * 8192 + g * 256 + lane2 * 4);
            float sc = lsc[a * 128 + col], sh = lsh[a * 128 + col];
            #pragma unroll
            for (int j = 0; j < 4; ++j) {
                float v = (float)o[j] * sc + sh;
                r[j] += __builtin_amdgcn_rcpf(1.0f + __expf(-v));
            }
        }
        #pragma unroll
        for (int j = 0; j < 4; ++j) {
            size_t off = (size_t)(row + j) * CCH + col;
            out[off] = r[j] * xf[off];
        }
    }
}

extern "C" void kernel_launch(void* const* d_in, const int* in_sizes, int n_in,
                              void* d_out, int out_size, void* d_ws, size_t ws_size,
                              hipStream_t stream) {
    const float* xf    = (const float*)d_in[0];
    const int*   nb    = (const int*)  d_in[1];
    const float* W     = (const float*)d_in[2];
    const float* gamma = (const float*)d_in[3];
    const float* beta  = (const float*)d_in[4];
    float* out = (float*)d_out;

    char* ws = (char*)d_ws;
    __bf16* xbf   = (__bf16*)(ws + XBF_OFF);
    __bf16* wt    = (__bf16*)(ws + WT_OFF);
    __bf16* outb  = (__bf16*)(ws + OUTB_OFF);
    float*  stats = (float*)(ws + STATS_OFF);

    const int prep_items = (NVOX + 1) * 16 + 3 * CCH * KTOT + 768;
    k_prep<<<(prep_items + 255) / 256, 256, 0, stream>>>(xf, xbf, W, wt, stats);
    k_gemm<<<dim3(PB, 3), 256, 0, stream>>>(xbf, wt, nb, outb, stats);
    k_final<<<2048, 256, 0, stream>>>(outb, xf, stats, gamma, beta, out);
}

// Round 6
// 442.476 us; speedup vs baseline: 1.3260x; 1.3260x over previous
//
#include <hip/hip_runtime.h>
#include <hip/hip_bf16.h>

#define NVOX 200000
#define CCH  128
#define KTOT 384
#define EPS_BN 1e-5f
#define PB   625          // persistent blocks per axis
#define TPB  5            // tiles per block (625*5 = 3125 = 200000/64)
#define NTILE 3125        // tiles per axis

typedef __bf16 bf16x8 __attribute__((ext_vector_type(8)));
typedef __bf16 bf16x4 __attribute__((ext_vector_type(4)));
typedef float  floatx4 __attribute__((ext_vector_type(4)));

// ---- workspace layout (bytes) ----
#define XBF_OFF    0ull
#define XBF_BYTES  ((size_t)(NVOX + 1) * CCH * 2)      // bf16 features + zero row
#define WT_OFF     (XBF_OFF + XBF_BYTES)
#define WT_BYTES   ((size_t)3 * CCH * KTOT * 2)        // WT[a][c][k] bf16
#define OUTB_OFF   (WT_OFF + WT_BYTES)
#define OUTB_BYTES ((size_t)3 * NVOX * CCH * 2)        // pre-BN out, D-layout, bf16
#define STATS_OFF  (OUTB_OFF + OUTB_BYTES)
#define STATS_BYTES ((size_t)3 * 2 * CCH * 4)          // sum/sumsq fp32

// Fused prep: cast x -> bf16 (+ zero sentinel row), transpose W -> WT, zero stats.
__global__ void k_prep(const float* __restrict__ xf, __bf16* __restrict__ xbf,
                       const float* __restrict__ W, __bf16* __restrict__ wt,
                       float* __restrict__ stats) {
    int idx = blockIdx.x * blockDim.x + threadIdx.x;
    const int XC = (NVOX + 1) * 16;                    // 8-channel chunks
    if (idx < XC) {
        float v[8];
        if (idx < NVOX * 16) {
            const float4* p = (const float4*)xf + (size_t)idx * 2;
            float4 f0 = p[0], f1 = p[1];
            v[0] = f0.x; v[1] = f0.y; v[2] = f0.z; v[3] = f0.w;
            v[4] = f1.x; v[5] = f1.y; v[6] = f1.z; v[7] = f1.w;
        } else {
            #pragma unroll
            for (int j = 0; j < 8; ++j) v[j] = 0.0f;
        }
        bf16x8 o;
        #pragma unroll
        for (int j = 0; j < 8; ++j) o[j] = (__bf16)v[j];
        *((bf16x8*)xbf + idx) = o;
    } else if (idx < XC + 3 * CCH * KTOT) {
        int j = idx - XC;
        int k = j % KTOT; int rem = j / KTOT;
        int c = rem % CCH;  int a = rem / CCH;
        int s = k >> 7, k0 = k & 127;
        wt[j] = (__bf16)W[(((size_t)(a * 3 + s) * CCH) + k0) * CCH + c];
    } else if (idx < XC + 3 * CCH * KTOT + 768) {
        stats[idx - XC - 3 * CCH * KTOT] = 0.0f;
    }
}

// Persistent-block GEMM.
// - A staged via global_load_lds (gathered global src, linear LDS dest, XOR-swizzle
//   on BOTH source chunk choice and fragment read).
// - C stored directly in MFMA D-layout (bf16x4 per lane, coalesced) -- no smemO,
//   no LDS round-trip, no bank conflicts; k_final decodes the layout.
// - Sparsity skip (MFMA side): ~95% of prev/next rows are the zero row. Per
//   (mt, src) group of 16 rows, if ALL rows are sentinel the A-reads + MFMAs are
//   skipped (wave-uniform scalar branch; exact-zero contributions -> bit-identical).
// - __launch_bounds__(256, 2): 256-VGPR cap. (256,3) forced VGPR=84 + scratch
//   spill of the resident B frags (round 4: FETCH 534MB, 345us). Do not tighten.
__launch_bounds__(256, 2)
__global__ void k_gemm(const __bf16* __restrict__ xbf, const __bf16* __restrict__ wt,
                       const int* __restrict__ nb, __bf16* __restrict__ outb,
                       float* __restrict__ stats) {
    __shared__ __align__(16) __bf16 smemA[64 * 384];   // A tile, linear (glds dest)
    __shared__ int s_pn[2][128];                       // double-buffered prev/next idx
    __shared__ int s_msk[2][2];                        // [buf][0]=prev 4-bit, [1]=next

    const int a    = blockIdx.y;
    const int tid  = threadIdx.x;
    const int w    = tid >> 6;
    const int lane = tid & 63;
    const int q    = lane >> 4;
    const int ln   = lane & 15;
    const int e    = ln & 7;       // row-XOR key for this lane's fragment rows

    // ---- B resident in registers for the whole block lifetime ----
    const __bf16* wbase = wt + (size_t)a * CCH * KTOT;
    bf16x8 B0[12], B1[12];
    #pragma unroll
    for (int ks = 0; ks < 12; ++ks) {
        B0[ks] = *(const bf16x8*)(wbase + (size_t)(w * 32 + ln) * KTOT + ks * 32 + q * 8);
        B1[ks] = *(const bf16x8*)(wbase + (size_t)(w * 32 + 16 + ln) * KTOT + ks * 32 + q * 8);
    }

    // per-column stats accumulated in registers across all tiles
    float s0 = 0.f, ss0 = 0.f, s1 = 0.f, ss1 = 0.f;

    // ---- prologue: pn + masks for tile 0; pn for tile 1 in r_pn ----
    int r_pn = 0;
    if (tid < 128) {
        const size_t nbase = (size_t)(a * 2 + (tid >> 6)) * NVOX + (tid & 63);
        r_pn = nb[nbase + blockIdx.x * 64];
        s_pn[0][tid] = r_pn;
    }
    {
        unsigned long long m = 0;
        if (tid < 128) m = __ballot(r_pn == NVOX);
        if (tid == 0 || tid == 64) {
            int pmv = 0;
            #pragma unroll
            for (int gg = 0; gg < 4; ++gg)
                if (((m >> (gg * 16)) & 0xFFFFull) == 0xFFFFull) pmv |= 1 << gg;
            s_msk[0][tid >> 6] = pmv;
        }
    }
    if (tid < 128)
        r_pn = nb[(size_t)(a * 2 + (tid >> 6)) * NVOX + (tid & 63) + (blockIdx.x + PB) * 64];
    __syncthreads();

    for (int ti = 0; ti < TPB; ++ti) {
        const int tIdx = blockIdx.x + ti * PB;
        const int row0 = tIdx * 64;
        const int buf  = ti & 1;

        // ---- issue gathered A tile straight into LDS (3072 x 16B chunks) ----
        #pragma unroll
        for (int it = 0; it < 12; ++it) {
            int p    = it * 256 + tid;       // linear LDS chunk index
            int r    = p / 48;               // row 0..63
            int spos = p - r * 48;           // swizzled slot within row
            int slog = spos ^ (r & 7);       // logical chunk: src*16 + ch
            int src  = slog >> 4, ch = slog & 15;
            int g    = (src == 1) ? (row0 + r) : s_pn[buf][(src >> 1) * 64 + r];
            const __bf16* gp = xbf + (size_t)g * CCH + ch * 8;
            __builtin_amdgcn_global_load_lds(
                (const __attribute__((address_space(1))) void*)gp,
                (__attribute__((address_space(3))) void*)(&smemA[(it * 256 + w * 64) * 8]),
                16, 0, 0);
        }
        // publish next tile's pn + validity masks (register ballot, no LDS read)
        if (ti + 1 < TPB) {
            if (tid < 128) s_pn[buf ^ 1][tid] = r_pn;
            unsigned long long m = 0;
            if (tid < 128) m = __ballot(r_pn == NVOX);
            if (tid == 0 || tid == 64) {
                int pmv = 0;
                #pragma unroll
                for (int gg = 0; gg < 4; ++gg)
                    if (((m >> (gg * 16)) & 0xFFFFull) == 0xFFFFull) pmv |= 1 << gg;
                s_msk[buf ^ 1][tid >> 6] = pmv;
            }
        }
        __syncthreads();   // BAR1: A landed (vmcnt drain) + prev stores drained

        // prefetch pn for tile ti+2 (latency hidden under MFMA)
        if (ti + 2 < TPB && tid < 128)
            r_pn = nb[(size_t)(a * 2 + (tid >> 6)) * NVOX
                      + (blockIdx.x + (ti + 2) * PB) * 64 + (tid & 63)];

        const int pm = __builtin_amdgcn_readfirstlane(s_msk[buf][0]);
        const int nm = __builtin_amdgcn_readfirstlane(s_msk[buf][1]);

        // ---- MFMA K-loop with per-(mt,src) sparsity skip ----
        floatx4 acc0[4], acc1[4];
        #pragma unroll
        for (int mt = 0; mt < 4; ++mt)
            #pragma unroll
            for (int r = 0; r < 4; ++r) { acc0[mt][r] = 0.0f; acc1[mt][r] = 0.0f; }

        #pragma unroll
        for (int mt = 0; mt < 4; ++mt) {
            const int rr = mt * 16 + ln;
            #pragma unroll
            for (int ks = 4; ks < 8; ++ks) {        // self: always
                bf16x8 afr = *(const bf16x8*)(&smemA[rr * 384 + (((ks * 4 + q) ^ e) * 8)]);
                acc0[mt] = __builtin_amdgcn_mfma_f32_16x16x32_bf16(afr, B0[ks], acc0[mt], 0, 0, 0);
                acc1[mt] = __builtin_amdgcn_mfma_f32_16x16x32_bf16(afr, B1[ks], acc1[mt], 0, 0, 0);
            }
            if (!((pm >> mt) & 1)) {
                #pragma unroll
                for (int ks = 0; ks < 4; ++ks) {    // prev
                    bf16x8 afr = *(const bf16x8*)(&smemA[rr * 384 + (((ks * 4 + q) ^ e) * 8)]);
                    acc0[mt] = __builtin_amdgcn_mfma_f32_16x16x32_bf16(afr, B0[ks], acc0[mt], 0, 0, 0);
                    acc1[mt] = __builtin_amdgcn_mfma_f32_16x16x32_bf16(afr, B1[ks], acc1[mt], 0, 0, 0);
                }
            }
            if (!((nm >> mt) & 1)) {
                #pragma unroll
                for (int ks = 8; ks < 12; ++ks) {   // next
                    bf16x8 afr = *(const bf16x8*)(&smemA[rr * 384 + (((ks * 4 + q) ^ e) * 8)]);
                    acc0[mt] = __builtin_amdgcn_mfma_f32_16x16x32_bf16(afr, B0[ks], acc0[mt], 0, 0, 0);
                    acc1[mt] = __builtin_amdgcn_mfma_f32_16x16x32_bf16(afr, B1[ks], acc1[mt], 0, 0, 0);
                }
            }
        }

        // ---- stats into register accumulators ----
        #pragma unroll
        for (int mt = 0; mt < 4; ++mt)
            #pragma unroll
            for (int r = 0; r < 4; ++r) {
                float v0 = acc0[mt][r]; s0 += v0; ss0 += v0 * v0;
                float v1 = acc1[mt][r]; s1 += v1; ss1 += v1 * v1;
            }

        __syncthreads();   // BAR2: all A-reads done; next glds may overwrite smemA

        // ---- direct D-layout stores: slot = ((w*2+nt)*4+mt)*256 + lane*4 + r ----
        {
            __bf16* ob = outb + ((size_t)(a * NTILE + tIdx)) * 8192 + lane * 4;
            #pragma unroll
            for (int mt = 0; mt < 4; ++mt) {
                bf16x4 v0, v1;
                #pragma unroll
                for (int r = 0; r < 4; ++r) { v0[r] = (__bf16)acc0[mt][r]; v1[r] = (__bf16)acc1[mt][r]; }
                *(bf16x4*)(ob + ((w * 2 + 0) * 4 + mt) * 256) = v0;
                *(bf16x4*)(ob + ((w * 2 + 1) * 4 + mt) * 256) = v1;
            }
        }
        // stores drain at next tile's BAR1 (covered by glds issue + other blocks)
    }

    // ---- epilogue: quad-reduce stats, one atomic set per block ----
    s0 += __shfl_xor(s0, 16); ss0 += __shfl_xor(ss0, 16);
    s0 += __shfl_xor(s0, 32); ss0 += __shfl_xor(ss0, 32);
    s1 += __shfl_xor(s1, 16); ss1 += __shfl_xor(ss1, 16);
    s1 += __shfl_xor(s1, 32); ss1 += __shfl_xor(ss1, 32);
    if (lane < 16) {
        int c0 = w * 32 + lane, c1 = w * 32 + 16 + lane;
        atomicAdd(&stats[a * 2 * CCH + c0], s0);
        atomicAdd(&stats[a * 2 * CCH + CCH + c0], ss0);
        atomicAdd(&stats[a * 2 * CCH + c1], s1);
        atomicAdd(&stats[a * 2 * CCH + CCH + c1], ss1);
    }
}

// Decode D-layout outb, apply BN+sigmoid, sum over axes, multiply by features.
// Chunk c -> (tile t, group g in [0,32), lane): 4 consecutive rows, one column.
__launch_bounds__(256)
__global__ void k_final(const __bf16* __restrict__ outb, const float* __restrict__ xf,
                        const float* __restrict__ stats, const float* __restrict__ gamma,
                        const float* __restrict__ beta, float* __restrict__ out) {
    __shared__ float lsc[384], lsh[384];
    int tid = threadIdx.x;
    for (int i = tid; i < 384; i += 256) {
        int a = i >> 7, c = i & 127;
        float mu  = stats[a * 256 + c] * (1.0f / NVOX);
        float var = stats[a * 256 + 128 + c] * (1.0f / NVOX) - mu * mu;
        float rs  = rsqrtf(var + EPS_BN);
        float g = gamma[i], b = beta[i];
        lsc[i] = rs * g;
        lsh[i] = b - mu * rs * g;
    }
    __syncthreads();
    const int total = NTILE * 2048;     // 8B chunks per axis
    for (int c = blockIdx.x * 256 + tid; c < total; c += gridDim.x * 256) {
        int t     = c >> 11;
        int cc    = c & 2047;
        int g     = cc >> 6;            // ((w*2+nt)*4 + mt)
        int lane2 = cc & 63;
        int mt    = g & 3, h = g >> 2;  // h = w*2+nt
        int qq    = lane2 >> 4, lnn = lane2 & 15;
        int col   = h * 16 + lnn;       // == w*32 + nt*16 + ln
        int row   = t * 64 + mt * 16 + qq * 4;
        float r[4] = {0.f, 0.f, 0.f, 0.f};
        #pragma unroll
        for (int a = 0; a < 3; ++a) {
            bf16x4 o = *(const bf16x4*)(outb + ((size_t)(a * NTILE + t)) * 8192 + g * 256 + lane2 * 4);
            float sc = lsc[a * 128 + col], sh = lsh[a * 128 + col];
            #pragma unroll
            for (int j = 0; j < 4; ++j) {
                float v = (float)o[j] * sc + sh;
                r[j] += __builtin_amdgcn_rcpf(1.0f + __expf(-v));
            }
        }
        #pragma unroll
        for (int j = 0; j < 4; ++j) {
            size_t off = (size_t)(row + j) * CCH + col;
            out[off] = r[j] * xf[off];
        }
    }
}

extern "C" void kernel_launch(void* const* d_in, const int* in_sizes, int n_in,
                              void* d_out, int out_size, void* d_ws, size_t ws_size,
                              hipStream_t stream) {
    const float* xf    = (const float*)d_in[0];
    const int*   nb    = (const int*)  d_in[1];
    const float* W     = (const float*)d_in[2];
    const float* gamma = (const float*)d_in[3];
    const float* beta  = (const float*)d_in[4];
    float* out = (float*)d_out;

    char* ws = (char*)d_ws;
    __bf16* xbf   = (__bf16*)(ws + XBF_OFF);
    __bf16* wt    = (__bf16*)(ws + WT_OFF);
    __bf16* outb  = (__bf16*)(ws + OUTB_OFF);
    float*  stats = (float*)(ws + STATS_OFF);

    const int prep_items = (NVOX + 1) * 16 + 3 * CCH * KTOT + 768;
    k_prep<<<(prep_items + 255) / 256, 256, 0, stream>>>(xf, xbf, W, wt, stats);
    k_gemm<<<dim3(PB, 3), 256, 0, stream>>>(xbf, wt, nb, outb, stats);
    k_final<<<2048, 256, 0, stream>>>(outb, xf, stats, gamma, beta, out);
}

// Round 7
// 442.004 us; speedup vs baseline: 1.3274x; 1.0011x over previous
//
#include <hip/hip_runtime.h>
#include <hip/hip_bf16.h>

#define NVOX 200000
#define CCH  128
#define KTOT 384
#define EPS_BN 1e-5f
#define PB   625          // persistent blocks per axis
#define TPB  5            // tiles per block (625*5 = 3125 = 200000/64)
#define NTILE 3125        // tiles per axis

typedef __bf16 bf16x8 __attribute__((ext_vector_type(8)));
typedef __bf16 bf16x4 __attribute__((ext_vector_type(4)));
typedef float  floatx4 __attribute__((ext_vector_type(4)));

// ---- workspace layout (bytes) ----
#define XBF_OFF    0ull
#define XBF_BYTES  ((size_t)(NVOX + 1) * CCH * 2)      // bf16 features + zero row
#define WT_OFF     (XBF_OFF + XBF_BYTES)
#define WT_BYTES   ((size_t)3 * CCH * KTOT * 2)        // WT[a][c][k] bf16
#define OUTB_OFF   (WT_OFF + WT_BYTES)
#define OUTB_BYTES ((size_t)3 * NVOX * CCH * 2)        // pre-BN out, D-layout, bf16
#define STATS_OFF  (OUTB_OFF + OUTB_BYTES)
#define STATS_BYTES ((size_t)3 * 2 * CCH * 4)          // sum/sumsq fp32

// Fused prep: cast x -> bf16 (+ zero sentinel row), transpose W -> WT, zero stats.
__global__ void k_prep(const float* __restrict__ xf, __bf16* __restrict__ xbf,
                       const float* __restrict__ W, __bf16* __restrict__ wt,
                       float* __restrict__ stats) {
    int idx = blockIdx.x * blockDim.x + threadIdx.x;
    const int XC = (NVOX + 1) * 16;                    // 8-channel chunks
    if (idx < XC) {
        float v[8];
        if (idx < NVOX * 16) {
            const float4* p = (const float4*)xf + (size_t)idx * 2;
            float4 f0 = p[0], f1 = p[1];
            v[0] = f0.x; v[1] = f0.y; v[2] = f0.z; v[3] = f0.w;
            v[4] = f1.x; v[5] = f1.y; v[6] = f1.z; v[7] = f1.w;
        } else {
            #pragma unroll
            for (int j = 0; j < 8; ++j) v[j] = 0.0f;
        }
        bf16x8 o;
        #pragma unroll
        for (int j = 0; j < 8; ++j) o[j] = (__bf16)v[j];
        *((bf16x8*)xbf + idx) = o;
    } else if (idx < XC + 3 * CCH * KTOT) {
        int j = idx - XC;
        int k = j % KTOT; int rem = j / KTOT;
        int c = rem % CCH;  int a = rem / CCH;
        int s = k >> 7, k0 = k & 127;
        wt[j] = (__bf16)W[(((size_t)(a * 3 + s) * CCH) + k0) * CCH + c];
    } else if (idx < XC + 3 * CCH * KTOT + 768) {
        stats[idx - XC - 3 * CCH * KTOT] = 0.0f;
    }
}

// Persistent-block GEMM.
// - A staged via global_load_lds (gathered global src, linear LDS dest, XOR-swizzle
//   on BOTH source chunk choice and fragment read).
// - C stored directly in MFMA D-layout (bf16x4 per lane, coalesced) -- no smemO.
// - Sparsity skip (MFMA side): per (mt, src) group of 16 rows, all-sentinel ->
//   skip A-reads + MFMAs (exact-zero contributions, bit-identical result).
// - OCCUPANCY IS PINNED: amdgpu_waves_per_eu(2,2). History: floating occupancy
//   target made the allocator spill the resident B frags three times --
//   r1 (unroll pressure, FETCH 259MB), r4 ((256,3) -> VGPR=84, FETCH 534MB),
//   r6 (branchy skip at 128-VGPR target, FETCH 156MB). Live set is B(96)+acc(32)
//   +temps ~ 160 VGPR; min=max=2 waves/EU budgets 256 and removes the incentive
//   to spill. Do not replace with a bare __launch_bounds__ min-waves hint.
__launch_bounds__(256)
__attribute__((amdgpu_waves_per_eu(2, 2)))
__global__ void k_gemm(const __bf16* __restrict__ xbf, const __bf16* __restrict__ wt,
                       const int* __restrict__ nb, __bf16* __restrict__ outb,
                       float* __restrict__ stats) {
    __shared__ __align__(16) __bf16 smemA[64 * 384];   // A tile, linear (glds dest)
    __shared__ int s_pn[2][128];                       // double-buffered prev/next idx
    __shared__ int s_msk[2][2];                        // [buf][0]=prev 4-bit, [1]=next

    const int a    = blockIdx.y;
    const int tid  = threadIdx.x;
    const int w    = tid >> 6;
    const int lane = tid & 63;
    const int q    = lane >> 4;
    const int ln   = lane & 15;
    const int e    = ln & 7;       // row-XOR key for this lane's fragment rows

    // ---- B resident in registers for the whole block lifetime ----
    const __bf16* wbase = wt + (size_t)a * CCH * KTOT;
    bf16x8 B0[12], B1[12];
    #pragma unroll
    for (int ks = 0; ks < 12; ++ks) {
        B0[ks] = *(const bf16x8*)(wbase + (size_t)(w * 32 + ln) * KTOT + ks * 32 + q * 8);
        B1[ks] = *(const bf16x8*)(wbase + (size_t)(w * 32 + 16 + ln) * KTOT + ks * 32 + q * 8);
    }

    // per-column stats accumulated in registers across all tiles
    float s0 = 0.f, ss0 = 0.f, s1 = 0.f, ss1 = 0.f;

    // ---- prologue: pn + masks for tile 0; pn for tile 1 in r_pn ----
    int r_pn = 0;
    if (tid < 128) {
        const size_t nbase = (size_t)(a * 2 + (tid >> 6)) * NVOX + (tid & 63);
        r_pn = nb[nbase + blockIdx.x * 64];
        s_pn[0][tid] = r_pn;
    }
    {
        unsigned long long m = 0;
        if (tid < 128) m = __ballot(r_pn == NVOX);
        if (tid == 0 || tid == 64) {
            int pmv = 0;
            #pragma unroll
            for (int gg = 0; gg < 4; ++gg)
                if (((m >> (gg * 16)) & 0xFFFFull) == 0xFFFFull) pmv |= 1 << gg;
            s_msk[0][tid >> 6] = pmv;
        }
    }
    if (tid < 128)
        r_pn = nb[(size_t)(a * 2 + (tid >> 6)) * NVOX + (tid & 63) + (blockIdx.x + PB) * 64];
    __syncthreads();

    for (int ti = 0; ti < TPB; ++ti) {
        const int tIdx = blockIdx.x + ti * PB;
        const int row0 = tIdx * 64;
        const int buf  = ti & 1;

        // ---- issue gathered A tile straight into LDS (3072 x 16B chunks) ----
        #pragma unroll
        for (int it = 0; it < 12; ++it) {
            int p    = it * 256 + tid;       // linear LDS chunk index
            int r    = p / 48;               // row 0..63
            int spos = p - r * 48;           // swizzled slot within row
            int slog = spos ^ (r & 7);       // logical chunk: src*16 + ch
            int src  = slog >> 4, ch = slog & 15;
            int g    = (src == 1) ? (row0 + r) : s_pn[buf][(src >> 1) * 64 + r];
            const __bf16* gp = xbf + (size_t)g * CCH + ch * 8;
            __builtin_amdgcn_global_load_lds(
                (const __attribute__((address_space(1))) void*)gp,
                (__attribute__((address_space(3))) void*)(&smemA[(it * 256 + w * 64) * 8]),
                16, 0, 0);
        }
        // publish next tile's pn + validity masks (register ballot, no LDS read)
        if (ti + 1 < TPB) {
            if (tid < 128) s_pn[buf ^ 1][tid] = r_pn;
            unsigned long long m = 0;
            if (tid < 128) m = __ballot(r_pn == NVOX);
            if (tid == 0 || tid == 64) {
                int pmv = 0;
                #pragma unroll
                for (int gg = 0; gg < 4; ++gg)
                    if (((m >> (gg * 16)) & 0xFFFFull) == 0xFFFFull) pmv |= 1 << gg;
                s_msk[buf ^ 1][tid >> 6] = pmv;
            }
        }
        __syncthreads();   // BAR1: A landed (vmcnt drain) + prev iter's reads done

        // prefetch pn for tile ti+2 (latency hidden under MFMA)
        if (ti + 2 < TPB && tid < 128)
            r_pn = nb[(size_t)(a * 2 + (tid >> 6)) * NVOX
                      + (blockIdx.x + (ti + 2) * PB) * 64 + (tid & 63)];

        const int pm = __builtin_amdgcn_readfirstlane(s_msk[buf][0]);
        const int nm = __builtin_amdgcn_readfirstlane(s_msk[buf][1]);

        // ---- MFMA K-loop with per-(mt,src) sparsity skip ----
        floatx4 acc0[4], acc1[4];
        #pragma unroll
        for (int mt = 0; mt < 4; ++mt)
            #pragma unroll
            for (int r = 0; r < 4; ++r) { acc0[mt][r] = 0.0f; acc1[mt][r] = 0.0f; }

        #pragma unroll
        for (int mt = 0; mt < 4; ++mt) {
            const int rr = mt * 16 + ln;
            #pragma unroll
            for (int ks = 4; ks < 8; ++ks) {        // self: always
                bf16x8 afr = *(const bf16x8*)(&smemA[rr * 384 + (((ks * 4 + q) ^ e) * 8)]);
                acc0[mt] = __builtin_amdgcn_mfma_f32_16x16x32_bf16(afr, B0[ks], acc0[mt], 0, 0, 0);
                acc1[mt] = __builtin_amdgcn_mfma_f32_16x16x32_bf16(afr, B1[ks], acc1[mt], 0, 0, 0);
            }
            if (!((pm >> mt) & 1)) {
                #pragma unroll
                for (int ks = 0; ks < 4; ++ks) {    // prev
                    bf16x8 afr = *(const bf16x8*)(&smemA[rr * 384 + (((ks * 4 + q) ^ e) * 8)]);
                    acc0[mt] = __builtin_amdgcn_mfma_f32_16x16x32_bf16(afr, B0[ks], acc0[mt], 0, 0, 0);
                    acc1[mt] = __builtin_amdgcn_mfma_f32_16x16x32_bf16(afr, B1[ks], acc1[mt], 0, 0, 0);
                }
            }
            if (!((nm >> mt) & 1)) {
                #pragma unroll
                for (int ks = 8; ks < 12; ++ks) {   // next
                    bf16x8 afr = *(const bf16x8*)(&smemA[rr * 384 + (((ks * 4 + q) ^ e) * 8)]);
                    acc0[mt] = __builtin_amdgcn_mfma_f32_16x16x32_bf16(afr, B0[ks], acc0[mt], 0, 0, 0);
                    acc1[mt] = __builtin_amdgcn_mfma_f32_16x16x32_bf16(afr, B1[ks], acc1[mt], 0, 0, 0);
                }
            }
        }

        // ---- stats + direct D-layout stores (registers/global only -> BEFORE
        //      BAR2, so acc dies before the barrier; shortens live ranges) ----
        {
            __bf16* ob = outb + ((size_t)(a * NTILE + tIdx)) * 8192 + lane * 4;
            #pragma unroll
            for (int mt = 0; mt < 4; ++mt) {
                bf16x4 v0, v1;
                #pragma unroll
                for (int r = 0; r < 4; ++r) {
                    float f0 = acc0[mt][r]; s0 += f0; ss0 += f0 * f0; v0[r] = (__bf16)f0;
                    float f1 = acc1[mt][r]; s1 += f1; ss1 += f1 * f1; v1[r] = (__bf16)f1;
                }
                *(bf16x4*)(ob + ((w * 2 + 0) * 4 + mt) * 256) = v0;
                *(bf16x4*)(ob + ((w * 2 + 1) * 4 + mt) * 256) = v1;
            }
        }

        __syncthreads();   // BAR2: all smemA reads done; next glds may overwrite
        // stores drain at next tile's BAR1 (overlapped with glds issue)
    }

    // ---- epilogue: quad-reduce stats, one atomic set per block ----
    s0 += __shfl_xor(s0, 16); ss0 += __shfl_xor(ss0, 16);
    s0 += __shfl_xor(s0, 32); ss0 += __shfl_xor(ss0, 32);
    s1 += __shfl_xor(s1, 16); ss1 += __shfl_xor(ss1, 16);
    s1 += __shfl_xor(s1, 32); ss1 += __shfl_xor(ss1, 32);
    if (lane < 16) {
        int c0 = w * 32 + lane, c1 = w * 32 + 16 + lane;
        atomicAdd(&stats[a * 2 * CCH + c0], s0);
        atomicAdd(&stats[a * 2 * CCH + CCH + c0], ss0);
        atomicAdd(&stats[a * 2 * CCH + c1], s1);
        atomicAdd(&stats[a * 2 * CCH + CCH + c1], ss1);
    }
}

// Decode D-layout outb, apply BN+sigmoid, sum over axes, multiply by features.
// Chunk c -> (tile t, group g in [0,32), lane): 4 consecutive rows, one column.
__launch_bounds__(256)
__global__ void k_final(const __bf16* __restrict__ outb, const float* __restrict__ xf,
                        const float* __restrict__ stats, const float* __restrict__ gamma,
                        const float* __restrict__ beta, float* __restrict__ out) {
    __shared__ float lsc[384], lsh[384];
    int tid = threadIdx.x;
    for (int i = tid; i < 384; i += 256) {
        int a = i >> 7, c = i & 127;
        float mu  = stats[a * 256 + c] * (1.0f / NVOX);
        float var = stats[a * 256 + 128 + c] * (1.0f / NVOX) - mu * mu;
        float rs  = rsqrtf(var + EPS_BN);
        float g = gamma[i], b = beta[i];
        lsc[i] = rs * g;
        lsh[i] = b - mu * rs * g;
    }
    __syncthreads();
    const int total = NTILE * 2048;     // 8B chunks per axis
    for (int c = blockIdx.x * 256 + tid; c < total; c += gridDim.x * 256) {
        int t     = c >> 11;
        int cc    = c & 2047;
        int g     = cc >> 6;            // ((w*2+nt)*4 + mt)
        int lane2 = cc & 63;
        int mt    = g & 3, h = g >> 2;  // h = w*2+nt
        int qq    = lane2 >> 4, lnn = lane2 & 15;
        int col   = h * 16 + lnn;       // == w*32 + nt*16 + ln
        int row   = t * 64 + mt * 16 + qq * 4;
        float r[4] = {0.f, 0.f, 0.f, 0.f};
        #pragma unroll
        for (int a = 0; a < 3; ++a) {
            bf16x4 o = *(const bf16x4*)(outb + ((size_t)(a * NTILE + t)) * 8192 + g * 256 + lane2 * 4);
            float sc = lsc[a * 128 + col], sh = lsh[a * 128 + col];
            #pragma unroll
            for (int j = 0; j < 4; ++j) {
                float v = (float)o[j] * sc + sh;
                r[j] += __builtin_amdgcn_rcpf(1.0f + __expf(-v));
            }
        }
        #pragma unroll
        for (int j = 0; j < 4; ++j) {
            size_t off = (size_t)(row + j) * CCH + col;
            out[off] = r[j] * xf[off];
        }
    }
}

extern "C" void kernel_launch(void* const* d_in, const int* in_sizes, int n_in,
                              void* d_out, int out_size, void* d_ws, size_t ws_size,
                              hipStream_t stream) {
    const float* xf    = (const float*)d_in[0];
    const int*   nb    = (const int*)  d_in[1];
    const float* W     = (const float*)d_in[2];
    const float* gamma = (const float*)d_in[3];
    const float* beta  = (const float*)d_in[4];
    float* out = (float*)d_out;

    char* ws = (char*)d_ws;
    __bf16* xbf   = (__bf16*)(ws + XBF_OFF);
    __bf16* wt    = (__bf16*)(ws + WT_OFF);
    __bf16* outb  = (__bf16*)(ws + OUTB_OFF);
    float*  stats = (float*)(ws + STATS_OFF);

    const int prep_items = (NVOX + 1) * 16 + 3 * CCH * KTOT + 768;
    k_prep<<<(prep_items + 255) / 256, 256, 0, stream>>>(xf, xbf, W, wt, stats);
    k_gemm<<<dim3(PB, 3), 256, 0, stream>>>(xbf, wt, nb, outb, stats);
    k_final<<<2048, 256, 0, stream>>>(outb, xf, stats, gamma, beta, out);
}

// Round 9
// 441.140 us; speedup vs baseline: 1.3300x; 1.0020x over previous
//
#include <hip/hip_runtime.h>
#include <hip/hip_bf16.h>

#define NVOX 200000
#define CCH  128
#define KTOT 384
#define EPS_BN 1e-5f
#define PB   625          // persistent blocks per axis
#define TPB  5            // tiles per block (625*5 = 3125 = 200000/64)
#define NTILE 3125        // tiles per axis

typedef __bf16 bf16x8 __attribute__((ext_vector_type(8)));
typedef __bf16 bf16x4 __attribute__((ext_vector_type(4)));
typedef float  floatx4 __attribute__((ext_vector_type(4)));

// ---- workspace layout (bytes) ----
#define XBF_OFF    0ull
#define XBF_BYTES  ((size_t)(NVOX + 1) * CCH * 2)      // bf16 features + zero row
#define WT_OFF     (XBF_OFF + XBF_BYTES)
#define WT_BYTES   ((size_t)3 * CCH * KTOT * 2)        // WT[a][c][k] bf16
#define OUTB_OFF   (WT_OFF + WT_BYTES)
#define OUTB_BYTES ((size_t)3 * NVOX * CCH * 2)        // pre-BN out, D-layout, bf16
#define STATS_OFF  (OUTB_OFF + OUTB_BYTES)
#define STATS_BYTES ((size_t)3 * 2 * CCH * 4)          // sum/sumsq fp32

// Fused prep: cast x -> bf16 (+ zero sentinel row), transpose W -> WT, zero stats.
__global__ void k_prep(const float* __restrict__ xf, __bf16* __restrict__ xbf,
                       const float* __restrict__ W, __bf16* __restrict__ wt,
                       float* __restrict__ stats) {
    int idx = blockIdx.x * blockDim.x + threadIdx.x;
    const int XC = (NVOX + 1) * 16;                    // 8-channel chunks
    if (idx < XC) {
        float v[8];
        if (idx < NVOX * 16) {
            const float4* p = (const float4*)xf + (size_t)idx * 2;
            float4 f0 = p[0], f1 = p[1];
            v[0] = f0.x; v[1] = f0.y; v[2] = f0.z; v[3] = f0.w;
            v[4] = f1.x; v[5] = f1.y; v[6] = f1.z; v[7] = f1.w;
        } else {
            #pragma unroll
            for (int j = 0; j < 8; ++j) v[j] = 0.0f;
        }
        bf16x8 o;
        #pragma unroll
        for (int j = 0; j < 8; ++j) o[j] = (__bf16)v[j];
        *((bf16x8*)xbf + idx) = o;
    } else if (idx < XC + 3 * CCH * KTOT) {
        int j = idx - XC;
        int k = j % KTOT; int rem = j / KTOT;
        int c = rem % CCH;  int a = rem / CCH;
        int s = k >> 7, k0 = k & 127;
        wt[j] = (__bf16)W[(((size_t)(a * 3 + s) * CCH) + k0) * CCH + c];
    } else if (idx < XC + 3 * CCH * KTOT + 768) {
        stats[idx - XC - 3 * CCH * KTOT] = 0.0f;
    }
}

// Persistent-block GEMM.
// - A staged via global_load_lds (gathered global src, linear LDS dest, XOR-swizzle
//   on BOTH source chunk choice and fragment read).
// - C stored directly in MFMA D-layout (bf16x4 per lane, coalesced) -- no smemO.
// - Sparsity skip (MFMA side): per (mt, src) group of 16 rows, all-sentinel ->
//   skip A-reads + MFMAs (exact-zero contributions, bit-identical result).
//
// OCCUPANCY / SPILL HISTORY (do not regress):
//   Live set = B frags (96 VGPR) + acc (32) + temps ~= 160 VGPR. Occupancy quanta:
//   3 waves/SIMD requires VGPR<=128 -> guaranteed spill of the B file.
//   r1/r4/r6/r7 all spilled (FETCH 94->156..534MB) whenever the RA could target
//   >2 waves/SIMD. r6 trigger: deleting smemO shrank LDS to 49.5KB, letting
//   3 blocks/CU fit -> RA clamped to 128 VGPR + scratch. amdgpu_waves_per_eu(2,2)
//   was silently ignored (r7: identical binary).
//   FIX: LDS_PAD bumps LDS to ~55.3KB so only 2 blocks/CU fit by LDS -> RA budget
//   becomes 256 VGPR -> ~160 allocates cleanly. The pad is load-bearing.
#define LDS_PAD 2560
__launch_bounds__(256, 2)
__global__ void k_gemm(const __bf16* __restrict__ xbf, const __bf16* __restrict__ wt,
                       const int* __restrict__ nb, __bf16* __restrict__ outb,
                       float* __restrict__ stats) {
    __shared__ __align__(16) __bf16 smemA[64 * 384 + LDS_PAD];  // A tile + occupancy pad
    __shared__ int s_pn[2][128];                       // double-buffered prev/next idx
    __shared__ int s_msk[2][2];                        // [buf][0]=prev 4-bit, [1]=next

    const int a    = blockIdx.y;
    const int tid  = threadIdx.x;
    const int w    = tid >> 6;
    const int lane = tid & 63;
    const int q    = lane >> 4;
    const int ln   = lane & 15;
    const int e    = ln & 7;       // row-XOR key for this lane's fragment rows

    // touch the pad so it cannot be elided (one store, never read)
    if (tid == 0) smemA[64 * 384 + (blockIdx.x & (LDS_PAD - 1))] = (__bf16)0.0f;

    // ---- B resident in registers for the whole block lifetime ----
    const __bf16* wbase = wt + (size_t)a * CCH * KTOT;
    bf16x8 B0[12], B1[12];
    #pragma unroll
    for (int ks = 0; ks < 12; ++ks) {
        B0[ks] = *(const bf16x8*)(wbase + (size_t)(w * 32 + ln) * KTOT + ks * 32 + q * 8);
        B1[ks] = *(const bf16x8*)(wbase + (size_t)(w * 32 + 16 + ln) * KTOT + ks * 32 + q * 8);
    }

    // per-column stats accumulated in registers across all tiles
    float s0 = 0.f, ss0 = 0.f, s1 = 0.f, ss1 = 0.f;

    // ---- prologue: pn + masks for tile 0; pn for tile 1 in r_pn ----
    int r_pn = 0;
    if (tid < 128) {
        const size_t nbase = (size_t)(a * 2 + (tid >> 6)) * NVOX + (tid & 63);
        r_pn = nb[nbase + blockIdx.x * 64];
        s_pn[0][tid] = r_pn;
    }
    {
        unsigned long long m = 0;
        if (tid < 128) m = __ballot(r_pn == NVOX);
        if (tid == 0 || tid == 64) {
            int pmv = 0;
            #pragma unroll
            for (int gg = 0; gg < 4; ++gg)
                if (((m >> (gg * 16)) & 0xFFFFull) == 0xFFFFull) pmv |= 1 << gg;
            s_msk[0][tid >> 6] = pmv;
        }
    }
    if (tid < 128)
        r_pn = nb[(size_t)(a * 2 + (tid >> 6)) * NVOX + (tid & 63) + (blockIdx.x + PB) * 64];
    __syncthreads();

    for (int ti = 0; ti < TPB; ++ti) {
        const int tIdx = blockIdx.x + ti * PB;
        const int row0 = tIdx * 64;
        const int buf  = ti & 1;

        // ---- issue gathered A tile straight into LDS (3072 x 16B chunks) ----
        #pragma unroll
        for (int it = 0; it < 12; ++it) {
            int p    = it * 256 + tid;       // linear LDS chunk index
            int r    = p / 48;               // row 0..63
            int spos = p - r * 48;           // swizzled slot within row
            int slog = spos ^ (r & 7);       // logical chunk: src*16 + ch
            int src  = slog >> 4, ch = slog & 15;
            int g    = (src == 1) ? (row0 + r) : s_pn[buf][(src >> 1) * 64 + r];
            const __bf16* gp = xbf + (size_t)g * CCH + ch * 8;
            __builtin_amdgcn_global_load_lds(
                (const __attribute__((address_space(1))) void*)gp,
                (__attribute__((address_space(3))) void*)(&smemA[(it * 256 + w * 64) * 8]),
                16, 0, 0);
        }
        // publish next tile's pn + validity masks (register ballot, no LDS read)
        if (ti + 1 < TPB) {
            if (tid < 128) s_pn[buf ^ 1][tid] = r_pn;
            unsigned long long m = 0;
            if (tid < 128) m = __ballot(r_pn == NVOX);
            if (tid == 0 || tid == 64) {
                int pmv = 0;
                #pragma unroll
                for (int gg = 0; gg < 4; ++gg)
                    if (((m >> (gg * 16)) & 0xFFFFull) == 0xFFFFull) pmv |= 1 << gg;
                s_msk[buf ^ 1][tid >> 6] = pmv;
            }
        }
        __syncthreads();   // BAR1: A landed (vmcnt drain) + prev iter's reads done

        // prefetch pn for tile ti+2 (latency hidden under MFMA)
        if (ti + 2 < TPB && tid < 128)
            r_pn = nb[(size_t)(a * 2 + (tid >> 6)) * NVOX
                      + (blockIdx.x + (ti + 2) * PB) * 64 + (tid & 63)];

        const int pm = __builtin_amdgcn_readfirstlane(s_msk[buf][0]);
        const int nm = __builtin_amdgcn_readfirstlane(s_msk[buf][1]);

        // ---- MFMA K-loop with per-(mt,src) sparsity skip ----
        floatx4 acc0[4], acc1[4];
        #pragma unroll
        for (int mt = 0; mt < 4; ++mt)
            #pragma unroll
            for (int r = 0; r < 4; ++r) { acc0[mt][r] = 0.0f; acc1[mt][r] = 0.0f; }

        #pragma unroll
        for (int mt = 0; mt < 4; ++mt) {
            const int rr = mt * 16 + ln;
            #pragma unroll
            for (int ks = 4; ks < 8; ++ks) {        // self: always
                bf16x8 afr = *(const bf16x8*)(&smemA[rr * 384 + (((ks * 4 + q) ^ e) * 8)]);
                acc0[mt] = __builtin_amdgcn_mfma_f32_16x16x32_bf16(afr, B0[ks], acc0[mt], 0, 0, 0);
                acc1[mt] = __builtin_amdgcn_mfma_f32_16x16x32_bf16(afr, B1[ks], acc1[mt], 0, 0, 0);
            }
            if (!((pm >> mt) & 1)) {
                #pragma unroll
                for (int ks = 0; ks < 4; ++ks) {    // prev
                    bf16x8 afr = *(const bf16x8*)(&smemA[rr * 384 + (((ks * 4 + q) ^ e) * 8)]);
                    acc0[mt] = __builtin_amdgcn_mfma_f32_16x16x32_bf16(afr, B0[ks], acc0[mt], 0, 0, 0);
                    acc1[mt] = __builtin_amdgcn_mfma_f32_16x16x32_bf16(afr, B1[ks], acc1[mt], 0, 0, 0);
                }
            }
            if (!((nm >> mt) & 1)) {
                #pragma unroll
                for (int ks = 8; ks < 12; ++ks) {   // next
                    bf16x8 afr = *(const bf16x8*)(&smemA[rr * 384 + (((ks * 4 + q) ^ e) * 8)]);
                    acc0[mt] = __builtin_amdgcn_mfma_f32_16x16x32_bf16(afr, B0[ks], acc0[mt], 0, 0, 0);
                    acc1[mt] = __builtin_amdgcn_mfma_f32_16x16x32_bf16(afr, B1[ks], acc1[mt], 0, 0, 0);
                }
            }
        }

        // ---- stats + direct D-layout stores (registers/global only -> BEFORE
        //      BAR2, so acc dies before the barrier; shortens live ranges) ----
        {
            __bf16* ob = outb + ((size_t)(a * NTILE + tIdx)) * 8192 + lane * 4;
            #pragma unroll
            for (int mt = 0; mt < 4; ++mt) {
                bf16x4 v0, v1;
                #pragma unroll
                for (int r = 0; r < 4; ++r) {
                    float f0 = acc0[mt][r]; s0 += f0; ss0 += f0 * f0; v0[r] = (__bf16)f0;
                    float f1 = acc1[mt][r]; s1 += f1; ss1 += f1 * f1; v1[r] = (__bf16)f1;
                }
                *(bf16x4*)(ob + ((w * 2 + 0) * 4 + mt) * 256) = v0;
                *(bf16x4*)(ob + ((w * 2 + 1) * 4 + mt) * 256) = v1;
            }
        }

        __syncthreads();   // BAR2: all smemA reads done; next glds may overwrite
        // stores drain at next tile's BAR1 (overlapped with glds issue)
    }

    // ---- epilogue: quad-reduce stats, one atomic set per block ----
    s0 += __shfl_xor(s0, 16); ss0 += __shfl_xor(ss0, 16);
    s0 += __shfl_xor(s0, 32); ss0 += __shfl_xor(ss0, 32);
    s1 += __shfl_xor(s1, 16); ss1 += __shfl_xor(ss1, 16);
    s1 += __shfl_xor(s1, 32); ss1 += __shfl_xor(ss1, 32);
    if (lane < 16) {
        int c0 = w * 32 + lane, c1 = w * 32 + 16 + lane;
        atomicAdd(&stats[a * 2 * CCH + c0], s0);
        atomicAdd(&stats[a * 2 * CCH + CCH + c0], ss0);
        atomicAdd(&stats[a * 2 * CCH + c1], s1);
        atomicAdd(&stats[a * 2 * CCH + CCH + c1], ss1);
    }
}

// Decode D-layout outb, apply BN+sigmoid, sum over axes, multiply by features.
// Chunk c -> (tile t, group g in [0,32), lane): 4 consecutive rows, one column.
__launch_bounds__(256)
__global__ void k_final(const __bf16* __restrict__ outb, const float* __restrict__ xf,
                        const float* __restrict__ stats, const float* __restrict__ gamma,
                        const float* __restrict__ beta, float* __restrict__ out) {
    __shared__ float lsc[384], lsh[384];
    int tid = threadIdx.x;
    for (int i = tid; i < 384; i += 256) {
        int a = i >> 7, c = i & 127;
        float mu  = stats[a * 256 + c] * (1.0f / NVOX);
        float var = stats[a * 256 + 128 + c] * (1.0f / NVOX) - mu * mu;
        float rs  = rsqrtf(var + EPS_BN);
        float g = gamma[i], b = beta[i];
        lsc[i] = rs * g;
        lsh[i] = b - mu * rs * g;
    }
    __syncthreads();
    const int total = NTILE * 2048;     // 8B chunks per axis
    for (int c = blockIdx.x * 256 + tid; c < total; c += gridDim.x * 256) {
        int t     = c >> 11;
        int cc    = c & 2047;
        int g     = cc >> 6;            // ((w*2+nt)*4 + mt)
        int lane2 = cc & 63;
        int mt    = g & 3, h = g >> 2;  // h = w*2+nt
        int qq    = lane2 >> 4, lnn = lane2 & 15;
        int col   = h * 16 + lnn;       // == w*32 + nt*16 + ln
        int row   = t * 64 + mt * 16 + qq * 4;
        float r[4] = {0.f, 0.f, 0.f, 0.f};
        #pragma unroll
        for (int a = 0; a < 3; ++a) {
            bf16x4 o = *(const bf16x4*)(outb + ((size_t)(a * NTILE + t)) * 8192 + g * 256 + lane2 * 4);
            float sc = lsc[a * 128 + col], sh = lsh[a * 128 + col];
            #pragma unroll
            for (int j = 0; j < 4; ++j) {
                float v = (float)o[j] * sc + sh;
                r[j] += __builtin_amdgcn_rcpf(1.0f + __expf(-v));
            }
        }
        #pragma unroll
        for (int j = 0; j < 4; ++j) {
            size_t off = (size_t)(row + j) * CCH + col;
            out[off] = r[j] * xf[off];
        }
    }
}

extern "C" void kernel_launch(void* const* d_in, const int* in_sizes, int n_in,
                              void* d_out, int out_size, void* d_ws, size_t ws_size,
                              hipStream_t stream) {
    const float* xf    = (const float*)d_in[0];
    const int*   nb    = (const int*)  d_in[1];
    const float* W     = (const float*)d_in[2];
    const float* gamma = (const float*)d_in[3];
    const float* beta  = (const float*)d_in[4];
    float* out = (float*)d_out;

    char* ws = (char*)d_ws;
    __bf16* xbf   = (__bf16*)(ws + XBF_OFF);
    __bf16* wt    = (__bf16*)(ws + WT_OFF);
    __bf16* outb  = (__bf16*)(ws + OUTB_OFF);
    float*  stats = (float*)(ws + STATS_OFF);

    const int prep_items = (NVOX + 1) * 16 + 3 * CCH * KTOT + 768;
    k_prep<<<(prep_items + 255) / 256, 256, 0, stream>>>(xf, xbf, W, wt, stats);
    k_gemm<<<dim3(PB, 3), 256, 0, stream>>>(xbf, wt, nb, outb, stats);
    k_final<<<2048, 256, 0, stream>>>(outb, xf, stats, gamma, beta, out);
}

// Round 10
// 371.662 us; speedup vs baseline: 1.5787x; 1.1869x over previous
//
#include <hip/hip_runtime.h>
#include <hip/hip_bf16.h>

#define NVOX 200000
#define CCH  128
#define KTOT 384
#define EPS_BN 1e-5f
#define PB   625          // persistent blocks per axis
#define TPB  5            // tiles per block (625*5 = 3125 = 200000/64)
#define NTILE 3125        // tiles per axis

typedef __bf16 bf16x8 __attribute__((ext_vector_type(8)));
typedef __bf16 bf16x4 __attribute__((ext_vector_type(4)));
typedef float  floatx4 __attribute__((ext_vector_type(4)));

// ---- workspace layout (bytes) ----
#define XBF_OFF    0ull
#define XBF_BYTES  ((size_t)(NVOX + 1) * CCH * 2)      // bf16 features + zero row
#define WT_OFF     (XBF_OFF + XBF_BYTES)
#define WT_BYTES   ((size_t)3 * CCH * KTOT * 2)        // WT[a][c][k] bf16
#define OUTB_OFF   (WT_OFF + WT_BYTES)
#define OUTB_BYTES ((size_t)3 * NVOX * CCH * 2)        // pre-BN out, D-layout, bf16
#define STATS_OFF  (OUTB_OFF + OUTB_BYTES)
#define STATS_BYTES ((size_t)3 * 2 * CCH * 4)          // sum/sumsq fp32

// Fused prep: cast x -> bf16 (+ zero sentinel row), transpose W -> WT, zero stats.
__global__ void k_prep(const float* __restrict__ xf, __bf16* __restrict__ xbf,
                       const float* __restrict__ W, __bf16* __restrict__ wt,
                       float* __restrict__ stats) {
    int idx = blockIdx.x * blockDim.x + threadIdx.x;
    const int XC = (NVOX + 1) * 16;                    // 8-channel chunks
    if (idx < XC) {
        float v[8];
        if (idx < NVOX * 16) {
            const float4* p = (const float4*)xf + (size_t)idx * 2;
            float4 f0 = p[0], f1 = p[1];
            v[0] = f0.x; v[1] = f0.y; v[2] = f0.z; v[3] = f0.w;
            v[4] = f1.x; v[5] = f1.y; v[6] = f1.z; v[7] = f1.w;
        } else {
            #pragma unroll
            for (int j = 0; j < 8; ++j) v[j] = 0.0f;
        }
        bf16x8 o;
        #pragma unroll
        for (int j = 0; j < 8; ++j) o[j] = (__bf16)v[j];
        *((bf16x8*)xbf + idx) = o;
    } else if (idx < XC + 3 * CCH * KTOT) {
        int j = idx - XC;
        int k = j % KTOT; int rem = j / KTOT;
        int c = rem % CCH;  int a = rem / CCH;
        int s = k >> 7, k0 = k & 127;
        wt[j] = (__bf16)W[(((size_t)(a * 3 + s) * CCH) + k0) * CCH + c];
    } else if (idx < XC + 3 * CCH * KTOT + 768) {
        stats[idx - XC - 3 * CCH * KTOT] = 0.0f;
    }
}

// Persistent-block GEMM.
// - A staged via global_load_lds (gathered global src, linear LDS dest, XOR-swizzle
//   on BOTH source chunk choice and fragment read).
// - C stored directly in MFMA D-layout (bf16x4 per lane, coalesced) -- no smemO.
// - MFMA K-loop is a straight ks=0..11 ladder. SPARSITY SKIP IS DELIBERATELY
//   REMOVED: the 12 scalar-branch regions (r3/r6/r7/r9) forced the scheduler to
//   hold temps across CFG joins -> spilled ~140MB/dispatch of scratch at
//   VGPR=128 (FETCH 94->152MB, WRITE 172->253MB, k_gemm 124->182us). The
//   branch-free ladder is r2's proven-clean form (VGPR=128, no spill).
// - LDS_PAD keeps LDS at ~55.3KB so only 2 blocks/CU fit (r4: when 3 blocks fit,
//   RA clamped to 84 VGPR and spilled the B file; FETCH 534MB). Load-bearing.
#define LDS_PAD 2560
__launch_bounds__(256, 2)
__global__ void k_gemm(const __bf16* __restrict__ xbf, const __bf16* __restrict__ wt,
                       const int* __restrict__ nb, __bf16* __restrict__ outb,
                       float* __restrict__ stats) {
    __shared__ __align__(16) __bf16 smemA[64 * 384 + LDS_PAD];  // A tile + occupancy pad
    __shared__ int s_pn[2][128];                       // double-buffered prev/next idx

    const int a    = blockIdx.y;
    const int tid  = threadIdx.x;
    const int w    = tid >> 6;
    const int lane = tid & 63;
    const int q    = lane >> 4;
    const int ln   = lane & 15;
    const int e    = ln & 7;       // row-XOR key for this lane's fragment rows

    // touch the pad so it cannot be elided (one store, never read)
    if (tid == 0) smemA[64 * 384 + (blockIdx.x & (LDS_PAD - 1))] = (__bf16)0.0f;

    // ---- B resident in registers for the whole block lifetime ----
    const __bf16* wbase = wt + (size_t)a * CCH * KTOT;
    bf16x8 B0[12], B1[12];
    #pragma unroll
    for (int ks = 0; ks < 12; ++ks) {
        B0[ks] = *(const bf16x8*)(wbase + (size_t)(w * 32 + ln) * KTOT + ks * 32 + q * 8);
        B1[ks] = *(const bf16x8*)(wbase + (size_t)(w * 32 + 16 + ln) * KTOT + ks * 32 + q * 8);
    }

    // per-column stats accumulated in registers across all tiles
    float s0 = 0.f, ss0 = 0.f, s1 = 0.f, ss1 = 0.f;

    // ---- prologue: pn for tile 0 published; pn for tile 1 in r_pn ----
    int r_pn = 0;
    if (tid < 128) {
        const size_t nbase = (size_t)(a * 2 + (tid >> 6)) * NVOX + (tid & 63);
        r_pn = nb[nbase + blockIdx.x * 64];
        s_pn[0][tid] = r_pn;
        r_pn = nb[nbase + (blockIdx.x + PB) * 64];
    }
    __syncthreads();

    for (int ti = 0; ti < TPB; ++ti) {
        const int tIdx = blockIdx.x + ti * PB;
        const int row0 = tIdx * 64;
        const int buf  = ti & 1;

        // ---- issue gathered A tile straight into LDS (3072 x 16B chunks) ----
        #pragma unroll
        for (int it = 0; it < 12; ++it) {
            int p    = it * 256 + tid;       // linear LDS chunk index
            int r    = p / 48;               // row 0..63
            int spos = p - r * 48;           // swizzled slot within row
            int slog = spos ^ (r & 7);       // logical chunk: src*16 + ch
            int src  = slog >> 4, ch = slog & 15;
            int g    = (src == 1) ? (row0 + r) : s_pn[buf][(src >> 1) * 64 + r];
            const __bf16* gp = xbf + (size_t)g * CCH + ch * 8;
            __builtin_amdgcn_global_load_lds(
                (const __attribute__((address_space(1))) void*)gp,
                (__attribute__((address_space(3))) void*)(&smemA[(it * 256 + w * 64) * 8]),
                16, 0, 0);
        }
        // publish next tile's pn indices
        if (ti + 1 < TPB && tid < 128) s_pn[buf ^ 1][tid] = r_pn;
        __syncthreads();   // BAR1: A landed (vmcnt drain) + prev iter's reads done

        // prefetch pn for tile ti+2 (latency hidden under MFMA)
        if (ti + 2 < TPB && tid < 128)
            r_pn = nb[(size_t)(a * 2 + (tid >> 6)) * NVOX
                      + (blockIdx.x + (ti + 2) * PB) * 64 + (tid & 63)];

        // ---- MFMA K-loop: straight ladder, LDS A frags x register B frags ----
        floatx4 acc0[4], acc1[4];
        #pragma unroll
        for (int mt = 0; mt < 4; ++mt)
            #pragma unroll
            for (int r = 0; r < 4; ++r) { acc0[mt][r] = 0.0f; acc1[mt][r] = 0.0f; }

        #pragma unroll
        for (int ks = 0; ks < 12; ++ks) {
            #pragma unroll
            for (int mt = 0; mt < 4; ++mt) {
                bf16x8 afr = *(const bf16x8*)(&smemA[(mt * 16 + ln) * 384 + (((ks * 4 + q) ^ e) * 8)]);
                acc0[mt] = __builtin_amdgcn_mfma_f32_16x16x32_bf16(afr, B0[ks], acc0[mt], 0, 0, 0);
                acc1[mt] = __builtin_amdgcn_mfma_f32_16x16x32_bf16(afr, B1[ks], acc1[mt], 0, 0, 0);
            }
        }

        // ---- stats + direct D-layout stores (registers/global only) ----
        {
            __bf16* ob = outb + ((size_t)(a * NTILE + tIdx)) * 8192 + lane * 4;
            #pragma unroll
            for (int mt = 0; mt < 4; ++mt) {
                bf16x4 v0, v1;
                #pragma unroll
                for (int r = 0; r < 4; ++r) {
                    float f0 = acc0[mt][r]; s0 += f0; ss0 += f0 * f0; v0[r] = (__bf16)f0;
                    float f1 = acc1[mt][r]; s1 += f1; ss1 += f1 * f1; v1[r] = (__bf16)f1;
                }
                *(bf16x4*)(ob + ((w * 2 + 0) * 4 + mt) * 256) = v0;
                *(bf16x4*)(ob + ((w * 2 + 1) * 4 + mt) * 256) = v1;
            }
        }

        __syncthreads();   // BAR2: all smemA reads done; next glds may overwrite
        // stores drain at next tile's BAR1 (overlapped with glds issue)
    }

    // ---- epilogue: quad-reduce stats, one atomic set per block ----
    s0 += __shfl_xor(s0, 16); ss0 += __shfl_xor(ss0, 16);
    s0 += __shfl_xor(s0, 32); ss0 += __shfl_xor(ss0, 32);
    s1 += __shfl_xor(s1, 16); ss1 += __shfl_xor(ss1, 16);
    s1 += __shfl_xor(s1, 32); ss1 += __shfl_xor(ss1, 32);
    if (lane < 16) {
        int c0 = w * 32 + lane, c1 = w * 32 + 16 + lane;
        atomicAdd(&stats[a * 2 * CCH + c0], s0);
        atomicAdd(&stats[a * 2 * CCH + CCH + c0], ss0);
        atomicAdd(&stats[a * 2 * CCH + c1], s1);
        atomicAdd(&stats[a * 2 * CCH + CCH + c1], ss1);
    }
}

// Decode D-layout outb, apply BN+sigmoid, sum over axes, multiply by features.
// Chunk c -> (tile t, group g in [0,32), lane): 4 consecutive rows, one column.
__launch_bounds__(256)
__global__ void k_final(const __bf16* __restrict__ outb, const float* __restrict__ xf,
                        const float* __restrict__ stats, const float* __restrict__ gamma,
                        const float* __restrict__ beta, float* __restrict__ out) {
    __shared__ float lsc[384], lsh[384];
    int tid = threadIdx.x;
    for (int i = tid; i < 384; i += 256) {
        int a = i >> 7, c = i & 127;
        float mu  = stats[a * 256 + c] * (1.0f / NVOX);
        float var = stats[a * 256 + 128 + c] * (1.0f / NVOX) - mu * mu;
        float rs  = rsqrtf(var + EPS_BN);
        float g = gamma[i], b = beta[i];
        lsc[i] = rs * g;
        lsh[i] = b - mu * rs * g;
    }
    __syncthreads();
    const int total = NTILE * 2048;     // 8B chunks per axis
    for (int c = blockIdx.x * 256 + tid; c < total; c += gridDim.x * 256) {
        int t     = c >> 11;
        int cc    = c & 2047;
        int g     = cc >> 6;            // ((w*2+nt)*4 + mt)
        int lane2 = cc & 63;
        int mt    = g & 3, h = g >> 2;  // h = w*2+nt
        int qq    = lane2 >> 4, lnn = lane2 & 15;
        int col   = h * 16 + lnn;       // == w*32 + nt*16 + ln
        int row   = t * 64 + mt * 16 + qq * 4;
        float r[4] = {0.f, 0.f, 0.f, 0.f};
        #pragma unroll
        for (int a = 0; a < 3; ++a) {
            bf16x4 o = *(const bf16x4*)(outb + ((size_t)(a * NTILE + t)) * 8192 + g * 256 + lane2 * 4);
            float sc = lsc[a * 128 + col], sh = lsh[a * 128 + col];
            #pragma unroll
            for (int j = 0; j < 4; ++j) {
                float v = (float)o[j] * sc + sh;
                r[j] += __builtin_amdgcn_rcpf(1.0f + __expf(-v));
            }
        }
        #pragma unroll
        for (int j = 0; j < 4; ++j) {
            size_t off = (size_t)(row + j) * CCH + col;
            out[off] = r[j] * xf[off];
        }
    }
}

extern "C" void kernel_launch(void* const* d_in, const int* in_sizes, int n_in,
                              void* d_out, int out_size, void* d_ws, size_t ws_size,
                              hipStream_t stream) {
    const float* xf    = (const float*)d_in[0];
    const int*   nb    = (const int*)  d_in[1];
    const float* W     = (const float*)d_in[2];
    const float* gamma = (const float*)d_in[3];
    const float* beta  = (const float*)d_in[4];
    float* out = (float*)d_out;

    char* ws = (char*)d_ws;
    __bf16* xbf   = (__bf16*)(ws + XBF_OFF);
    __bf16* wt    = (__bf16*)(ws + WT_OFF);
    __bf16* outb  = (__bf16*)(ws + OUTB_OFF);
    float*  stats = (float*)(ws + STATS_OFF);

    const int prep_items = (NVOX + 1) * 16 + 3 * CCH * KTOT + 768;
    k_prep<<<(prep_items + 255) / 256, 256, 0, stream>>>(xf, xbf, W, wt, stats);
    k_gemm<<<dim3(PB, 3), 256, 0, stream>>>(xbf, wt, nb, outb, stats);
    k_final<<<2048, 256, 0, stream>>>(outb, xf, stats, gamma, beta, out);
}

// Round 11
// 350.874 us; speedup vs baseline: 1.6722x; 1.0592x over previous
//
#include <hip/hip_runtime.h>
#include <hip/hip_bf16.h>

#define NVOX 200000
#define CCH  128
#define KTOT 384
#define EPS_BN 1e-5f
#define PB    625         // persistent blocks per axis
#define TROWS 32          // rows per tile
#define TPB   10          // tiles per block (625*10*32 = 200000)
#define NT2   6250        // tiles per axis

typedef __bf16 bf16x8 __attribute__((ext_vector_type(8)));
typedef __bf16 bf16x4 __attribute__((ext_vector_type(4)));
typedef float  floatx4 __attribute__((ext_vector_type(4)));

// ---- workspace layout (bytes) ----
#define XBF_OFF    0ull
#define XBF_BYTES  ((size_t)(NVOX + 1) * CCH * 2)      // bf16 features + zero row
#define WT_OFF     (XBF_OFF + XBF_BYTES)
#define WT_BYTES   ((size_t)3 * CCH * KTOT * 2)        // WT[a][c][k] bf16
#define OUTB_OFF   (WT_OFF + WT_BYTES)
#define OUTB_BYTES ((size_t)3 * NVOX * CCH * 2)        // pre-BN out, D-layout, bf16
#define STATS_OFF  (OUTB_OFF + OUTB_BYTES)
#define STATS_BYTES ((size_t)3 * 2 * CCH * 4)          // sum/sumsq fp32

// Fused prep: cast x -> bf16 (+ zero sentinel row), transpose W -> WT, zero stats.
__global__ void k_prep(const float* __restrict__ xf, __bf16* __restrict__ xbf,
                       const float* __restrict__ W, __bf16* __restrict__ wt,
                       float* __restrict__ stats) {
    int idx = blockIdx.x * blockDim.x + threadIdx.x;
    const int XC = (NVOX + 1) * 16;                    // 8-channel chunks
    if (idx < XC) {
        float v[8];
        if (idx < NVOX * 16) {
            const float4* p = (const float4*)xf + (size_t)idx * 2;
            float4 f0 = p[0], f1 = p[1];
            v[0] = f0.x; v[1] = f0.y; v[2] = f0.z; v[3] = f0.w;
            v[4] = f1.x; v[5] = f1.y; v[6] = f1.z; v[7] = f1.w;
        } else {
            #pragma unroll
            for (int j = 0; j < 8; ++j) v[j] = 0.0f;
        }
        bf16x8 o;
        #pragma unroll
        for (int j = 0; j < 8; ++j) o[j] = (__bf16)v[j];
        *((bf16x8*)xbf + idx) = o;
    } else if (idx < XC + 3 * CCH * KTOT) {
        int j = idx - XC;
        int k = j % KTOT; int rem = j / KTOT;
        int c = rem % CCH;  int a = rem / CCH;
        int s = k >> 7, k0 = k & 127;
        wt[j] = (__bf16)W[(((size_t)(a * 3 + s) * CCH) + k0) * CCH + c];
    } else if (idx < XC + 3 * CCH * KTOT + 768) {
        stats[idx - XC - 3 * CCH * KTOT] = 0.0f;
    }
}

// Persistent-block GEMM, 2-phase software pipeline (guide T3-minimum):
//   per tile: publish pn(ti+1) -> __syncthreads (implicit vmcnt(0) = tile ti's
//   gather complete) -> ISSUE gather(ti+1 -> buf^1) -> MFMA(buf) -> stores.
//   The gather for ti+1 is in flight across a full tile of MFMA+stores, so the
//   next barrier's drain waits only residual latency (r10 waited the full
//   L2/HBM service time every tile: the ~50us gap above the LDS/HBM floors).
// - 32-row tiles, double-buffered LDS A (2x24KB). XOR-swizzle on BOTH the
//   gather-source chunk choice and the fragment read (rule #21).
// - C stored directly in MFMA D-layout (bf16x4/lane, coalesced); k_final decodes.
// - Straight-line MFMA ladder: NO sparsity skip, NO branches around MFMA
//   (r9: 12 branch regions -> RA spill, FETCH +60MB, +69us. Do not reintroduce.)
// - LDS_PAD keeps LDS ~54.8KB so only 2 blocks/CU fit -> RA budget 256 VGPR.
//   (r4/r6: when 3 blocks fit by LDS, RA clamps to <=128 and spills B. Load-bearing.)
#define LDS_PAD 2560
__launch_bounds__(256, 2)
__global__ void k_gemm(const __bf16* __restrict__ xbf, const __bf16* __restrict__ wt,
                       const int* __restrict__ nb, __bf16* __restrict__ outb,
                       float* __restrict__ stats) {
    __shared__ __align__(16) __bf16 smemA[2][TROWS * 384];   // 2 x 24KB
    __shared__ __bf16 smemPad[LDS_PAD];                      // occupancy pad
    __shared__ int s_pn[2][64];                              // per-tile prev/next idx

    const int a    = blockIdx.y;
    const int tid  = threadIdx.x;
    const int w    = tid >> 6;
    const int lane = tid & 63;
    const int q    = lane >> 4;
    const int ln   = lane & 15;
    const int e    = ln & 7;       // row-XOR key for this lane's fragment rows

    // touch the pad so it cannot be elided (one store, never read)
    if (tid == 0) smemPad[blockIdx.x & (LDS_PAD - 1)] = (__bf16)0.0f;

    // ---- B resident in registers for the whole block lifetime ----
    const __bf16* wbase = wt + (size_t)a * CCH * KTOT;
    bf16x8 B0[12], B1[12];
    #pragma unroll
    for (int ks = 0; ks < 12; ++ks) {
        B0[ks] = *(const bf16x8*)(wbase + (size_t)(w * 32 + ln) * KTOT + ks * 32 + q * 8);
        B1[ks] = *(const bf16x8*)(wbase + (size_t)(w * 32 + 16 + ln) * KTOT + ks * 32 + q * 8);
    }

    // per-column stats accumulated in registers across all tiles
    float s0 = 0.f, ss0 = 0.f, s1 = 0.f, ss1 = 0.f;

    // ---- prologue: pn(tile0) published; issue gather(tile0); pn(tile1) in r_pn ----
    int r_pn = 0;
    if (tid < 64) {
        const size_t nbase = (size_t)(a * 2 + (tid >> 5)) * NVOX + (tid & 31);
        r_pn = nb[nbase + blockIdx.x * TROWS];
        s_pn[0][tid] = r_pn;
        r_pn = nb[nbase + (blockIdx.x + PB) * TROWS];
    }
    __syncthreads();
    {   // issue gather for tile 0 into buf 0 (1536 x 16B chunks)
        const int row0 = blockIdx.x * TROWS;
        #pragma unroll
        for (int it = 0; it < 6; ++it) {
            int p    = it * 256 + tid;
            int r    = p / 48;
            int seg  = p - r * 48;
            int slog = seg ^ (r & 7);
            int src  = slog >> 4, ch = slog & 15;
            int g    = (src == 1) ? (row0 + r) : s_pn[0][(src >> 1) * 32 + r];
            __builtin_amdgcn_global_load_lds(
                (const __attribute__((address_space(1))) void*)(xbf + (size_t)g * CCH + ch * 8),
                (__attribute__((address_space(3))) void*)(&smemA[0][(it * 256 + w * 64) * 8]),
                16, 0, 0);
        }
    }

    for (int ti = 0; ti < TPB; ++ti) {
        const int tIdx = blockIdx.x + ti * PB;
        const int buf  = ti & 1;

        // publish pn for tile ti+1 (slot buf^1 was last read one barrier ago)
        if (ti + 1 < TPB && tid < 64) s_pn[buf ^ 1][tid] = r_pn;
        __syncthreads();   // implicit vmcnt(0): gather(ti) landed; s_pn visible;
                           // prev iter's smemA[buf^1] reads all complete

        // ---- issue gather for tile ti+1 into buf^1 (in flight across MFMA) ----
        if (ti + 1 < TPB) {
            const int rown = (blockIdx.x + (ti + 1) * PB) * TROWS;
            #pragma unroll
            for (int it = 0; it < 6; ++it) {
                int p    = it * 256 + tid;
                int r    = p / 48;
                int seg  = p - r * 48;
                int slog = seg ^ (r & 7);
                int src  = slog >> 4, ch = slog & 15;
                int g    = (src == 1) ? (rown + r) : s_pn[buf ^ 1][(src >> 1) * 32 + r];
                __builtin_amdgcn_global_load_lds(
                    (const __attribute__((address_space(1))) void*)(xbf + (size_t)g * CCH + ch * 8),
                    (__attribute__((address_space(3))) void*)(&smemA[buf ^ 1][(it * 256 + w * 64) * 8]),
                    16, 0, 0);
            }
        }
        // prefetch pn for tile ti+2 (latency hidden under MFMA)
        if (ti + 2 < TPB && tid < 64)
            r_pn = nb[(size_t)(a * 2 + (tid >> 5)) * NVOX
                      + (blockIdx.x + (ti + 2) * PB) * TROWS + (tid & 31)];

        // ---- MFMA ladder on buf (tile ti) ----
        floatx4 acc0[2], acc1[2];
        #pragma unroll
        for (int mt = 0; mt < 2; ++mt)
            #pragma unroll
            for (int r = 0; r < 4; ++r) { acc0[mt][r] = 0.0f; acc1[mt][r] = 0.0f; }

        #pragma unroll
        for (int ks = 0; ks < 12; ++ks) {
            #pragma unroll
            for (int mt = 0; mt < 2; ++mt) {
                bf16x8 afr = *(const bf16x8*)(&smemA[buf][(mt * 16 + ln) * 384 + (((ks * 4 + q) ^ e) * 8)]);
                acc0[mt] = __builtin_amdgcn_mfma_f32_16x16x32_bf16(afr, B0[ks], acc0[mt], 0, 0, 0);
                acc1[mt] = __builtin_amdgcn_mfma_f32_16x16x32_bf16(afr, B1[ks], acc1[mt], 0, 0, 0);
            }
        }

        // ---- stats + direct D-layout stores (registers/global only) ----
        {
            __bf16* ob = outb + ((size_t)(a * NT2 + tIdx)) * 4096 + lane * 4;
            #pragma unroll
            for (int mt = 0; mt < 2; ++mt) {
                bf16x4 v0, v1;
                #pragma unroll
                for (int r = 0; r < 4; ++r) {
                    float f0 = acc0[mt][r]; s0 += f0; ss0 += f0 * f0; v0[r] = (__bf16)f0;
                    float f1 = acc1[mt][r]; s1 += f1; ss1 += f1 * f1; v1[r] = (__bf16)f1;
                }
                *(bf16x4*)(ob + ((w * 2 + 0) * 2 + mt) * 256) = v0;
                *(bf16x4*)(ob + ((w * 2 + 1) * 2 + mt) * 256) = v1;
            }
        }
        // gather(ti+1) + these stores drain at the next iteration's barrier
    }

    // ---- epilogue: quad-reduce stats, one atomic set per block ----
    s0 += __shfl_xor(s0, 16); ss0 += __shfl_xor(ss0, 16);
    s0 += __shfl_xor(s0, 32); ss0 += __shfl_xor(ss0, 32);
    s1 += __shfl_xor(s1, 16); ss1 += __shfl_xor(ss1, 16);
    s1 += __shfl_xor(s1, 32); ss1 += __shfl_xor(ss1, 32);
    if (lane < 16) {
        int c0 = w * 32 + lane, c1 = w * 32 + 16 + lane;
        atomicAdd(&stats[a * 2 * CCH + c0], s0);
        atomicAdd(&stats[a * 2 * CCH + CCH + c0], ss0);
        atomicAdd(&stats[a * 2 * CCH + c1], s1);
        atomicAdd(&stats[a * 2 * CCH + CCH + c1], ss1);
    }
}

// Tile-based finalize: one 32-row tile per block.
// Phase 1: read outb coalesced in D-layout, BN+sigmoid, sum axes in registers.
// Phase 2: scatter sums to a padded [32][132] LDS tile (2-way conflicts = free).
// Phase 3: read LDS row-major, multiply by xf, write out -- xf/out accesses are
// full-128B-line coalesced (r6-r10's direct decode wrote scattered 64B segments:
// partial-line RMW, ~24us penalty vs the r0-r2 row-major k_final).
__launch_bounds__(256)
__global__ void k_final(const __bf16* __restrict__ outb, const float* __restrict__ xf,
                        const float* __restrict__ stats, const float* __restrict__ gamma,
                        const float* __restrict__ beta, float* __restrict__ out) {
    __shared__ float lsc[384], lsh[384];
    __shared__ float tile[TROWS * 132];
    const int tid = threadIdx.x;
    for (int i = tid; i < 384; i += 256) {
        int a = i >> 7, c = i & 127;
        float mu  = stats[a * 256 + c] * (1.0f / NVOX);
        float var = stats[a * 256 + 128 + c] * (1.0f / NVOX) - mu * mu;
        float rs  = rsqrtf(var + EPS_BN);
        float g = gamma[i], b = beta[i];
        lsc[i] = rs * g;
        lsh[i] = b - mu * rs * g;
    }
    __syncthreads();

    const int t = blockIdx.x;           // one tile (32 rows) per block; grid = NT2

    // ---- phase 1: sigmoid-sum in D-layout positions (registers) ----
    float racc[16];
    #pragma unroll
    for (int j = 0; j < 16; ++j) racc[j] = 0.0f;
    #pragma unroll
    for (int a = 0; a < 3; ++a) {
        #pragma unroll
        for (int k = 0; k < 4; ++k) {
            int cidx = k * 256 + tid;   // 1024 bf16x4 chunks per (a, t)
            bf16x4 o = *(const bf16x4*)(outb + ((size_t)(a * NT2 + t)) * 4096 + cidx * 4);
            int g = cidx >> 6, l2 = cidx & 63;
            int col = (g >> 1) * 16 + (l2 & 15);
            float sc = lsc[a * 128 + col], sh = lsh[a * 128 + col];
            #pragma unroll
            for (int j = 0; j < 4; ++j) {
                float v = (float)o[j] * sc + sh;
                racc[k * 4 + j] += __builtin_amdgcn_rcpf(1.0f + __expf(-v));
            }
        }
    }

    // ---- phase 2: scatter to LDS row-major ([32][132] padded) ----
    #pragma unroll
    for (int k = 0; k < 4; ++k) {
        int cidx = k * 256 + tid;
        int g = cidx >> 6, l2 = cidx & 63;
        int row = (g & 1) * 16 + (l2 >> 4) * 4;
        int col = (g >> 1) * 16 + (l2 & 15);
        #pragma unroll
        for (int j = 0; j < 4; ++j)
            tile[(row + j) * 132 + col] = racc[k * 4 + j];
    }
    __syncthreads();

    // ---- phase 3: coalesced multiply + store (full 128B lines) ----
    #pragma unroll
    for (int k = 0; k < 4; ++k) {
        int fc  = k * 256 + tid;        // 1024 float4 chunks = 32 rows x 32
        int row = fc >> 5, c4 = fc & 31;
        float4 v = *(float4*)&tile[row * 132 + c4 * 4];
        size_t f4idx = (size_t)(t * TROWS + row) * 32 + c4;
        float4 f = ((const float4*)xf)[f4idx];
        float4 o;
        o.x = v.x * f.x; o.y = v.y * f.y; o.z = v.z * f.z; o.w = v.w * f.w;
        ((float4*)out)[f4idx] = o;
    }
}

extern "C" void kernel_launch(void* const* d_in, const int* in_sizes, int n_in,
                              void* d_out, int out_size, void* d_ws, size_t ws_size,
                              hipStream_t stream) {
    const float* xf    = (const float*)d_in[0];
    const int*   nb    = (const int*)  d_in[1];
    const float* W     = (const float*)d_in[2];
    const float* gamma = (const float*)d_in[3];
    const float* beta  = (const float*)d_in[4];
    float* out = (float*)d_out;

    char* ws = (char*)d_ws;
    __bf16* xbf   = (__bf16*)(ws + XBF_OFF);
    __bf16* wt    = (__bf16*)(ws + WT_OFF);
    __bf16* outb  = (__bf16*)(ws + OUTB_OFF);
    float*  stats = (float*)(ws + STATS_OFF);

    const int prep_items = (NVOX + 1) * 16 + 3 * CCH * KTOT + 768;
    k_prep<<<(prep_items + 255) / 256, 256, 0, stream>>>(xf, xbf, W, wt, stats);
    k_gemm<<<dim3(PB, 3), 256, 0, stream>>>(xbf, wt, nb, outb, stats);
    k_final<<<NT2, 256, 0, stream>>>(outb, xf, stats, gamma, beta, out);
}